// Round 3
// baseline (349.514 us; speedup 1.0000x reference)
//
#include <hip/hip_runtime.h>
#include <hip/hip_bf16.h>
#include <stdint.h>

#define B_DIM 8192
#define K_DIM 2048
#define N_DIM 2048
#define NSEG 4
#define NT (K_DIM / 64)   // 32 K-tiles of BK=64

typedef short bf16x8 __attribute__((ext_vector_type(8)));   // 8 bf16 (4 VGPRs)
typedef float f32x16 __attribute__((ext_vector_type(16)));
typedef unsigned short ushort8v __attribute__((ext_vector_type(8)));

typedef const __attribute__((address_space(1))) void* gas_ptr;
typedef __attribute__((address_space(3))) void* lds_ptr;

__device__ __forceinline__ unsigned short f2bf(float f) {
  uint32_t u = __float_as_uint(f);
  u += 0x7FFFu + ((u >> 16) & 1u);   // round-to-nearest-even
  return (unsigned short)(u >> 16);
}

// ---------------- W: f32 -> bf16 conversion, 8 elems/thread ----------------
__global__ __launch_bounds__(256)
void convert_kernel(const float* __restrict__ in, unsigned short* __restrict__ out, int n8) {
  int i = blockIdx.x * blockDim.x + threadIdx.x;
  const int stride = gridDim.x * blockDim.x;
  for (; i < n8; i += stride) {
    const float4* p = (const float4*)(in + (size_t)i * 8);
    float4 v0 = p[0];
    float4 v1 = p[1];
    ushort8v r;
    r[0] = f2bf(v0.x); r[1] = f2bf(v0.y); r[2] = f2bf(v0.z); r[3] = f2bf(v0.w);
    r[4] = f2bf(v1.x); r[5] = f2bf(v1.y); r[6] = f2bf(v1.z); r[7] = f2bf(v1.w);
    *(ushort8v*)(out + (size_t)i * 8) = r;
  }
}

// ------ fused: x f32 -> bf16 convert + gates = sigmoid(x @ Wg^T + bg) ------
__global__ __launch_bounds__(256)
void xconv_gates_kernel(const float* __restrict__ x, const float* __restrict__ Wg,
                        const float* __restrict__ bg,
                        unsigned short* __restrict__ xb, float* __restrict__ gates) {
  const int b = blockIdx.x;
  const int tid = threadIdx.x;
  const size_t base = (size_t)b * K_DIM + tid * 8;
  const float4 v0 = *(const float4*)(x + base);
  const float4 v1 = *(const float4*)(x + base + 4);
  ushort8v r;
  r[0] = f2bf(v0.x); r[1] = f2bf(v0.y); r[2] = f2bf(v0.z); r[3] = f2bf(v0.w);
  r[4] = f2bf(v1.x); r[5] = f2bf(v1.y); r[6] = f2bf(v1.z); r[7] = f2bf(v1.w);
  *(ushort8v*)(xb + base) = r;

  float a[4];
#pragma unroll
  for (int s = 0; s < 4; ++s) {
    const float4 w0 = *(const float4*)(Wg + (size_t)s * K_DIM + tid * 8);
    const float4 w1 = *(const float4*)(Wg + (size_t)s * K_DIM + tid * 8 + 4);
    a[s] = v0.x * w0.x + v0.y * w0.y + v0.z * w0.z + v0.w * w0.w
         + v1.x * w1.x + v1.y * w1.y + v1.z * w1.z + v1.w * w1.w;
  }
#pragma unroll
  for (int off = 1; off < 64; off <<= 1) {
#pragma unroll
    for (int s = 0; s < 4; ++s) a[s] += __shfl_xor(a[s], off);
  }
  __shared__ float red[4][4];
  const int wv = tid >> 6;
  if ((tid & 63) == 0) {
#pragma unroll
    for (int s = 0; s < 4; ++s) red[wv][s] = a[s];
  }
  __syncthreads();
  if (tid < 4) {
    float v = red[0][tid] + red[1][tid] + red[2][tid] + red[3][tid] + bg[tid];
    gates[(size_t)b * 4 + tid] = 1.f / (1.f + __expf(-v));
  }
}

// ------------- fused 4-segment GEMM, 32x32x16 MFMA, 8-phase-style -----------
// Block: 256 batch rows x 64 d-cols x 4 segs (eff 256x256). 8 waves = 4M x 2D:
// wave (wm,wd) owns rows wm*64..+64, d-cols wd*32..+32, ALL 4 segs in-lane.
// Per K-tile (BK=64): 4 kstep-major phases, each 8 x mfma_32x32x16 (= same
// FLOP as 16 x 16x16x32) + 6 ds_read_b128 + 2 global_load_lds.
// LDS 160 KiB: A dbuf 2x32K | B TRIPLE-buffered 3x32K (B(t+2) stage target is
// provably dead: it held B(t-1), fully consumed before tile t began).
// vmcnt: 12 in flight at tile end, wait to 4 (A(t+1)+B(t+1) done, B(t+2) fly).
__global__ __launch_bounds__(512, 2)
void seg_gemm_kernel(const unsigned short* __restrict__ Xb,
                     const unsigned short* __restrict__ Wb,
                     const float* __restrict__ b_seg,
                     const float* __restrict__ thr,
                     const float* __restrict__ gates,
                     float* __restrict__ out) {
  extern __shared__ __align__(128) char smem[];   // 163840 bytes

  const int tid = threadIdx.x;
  const int lane = tid & 63;
  const int wid = tid >> 6;
  const int wm = wid >> 1;        // 0..3 (m)
  const int wd = wid & 1;         // 0..1 (d-col half)

  // bijective XCD swizzle: 1024 blocks, 8 XCDs, 128 per XCD
  const int id = blockIdx.x;
  const int swz = (id & 7) * 128 + (id >> 3);
  const int m0 = (swz >> 5) * 256;
  const int n0 = (swz & 31) * 64;

  // ---- staging constants (identical layout to R2; verified algebraically) --
  const int row_st = ((tid >> 7) << 4) + ((tid >> 2) & 15);          // + j*64
  const int kb_st  = (((tid >> 6) & 1) << 6) + ((((tid & 3) << 4)) ^ (((tid >> 5) & 1) << 5));
  const int ke_st  = kb_st >> 1;
  const int ldsd   = tid * 16;

  // ---- read constants (32x32x16 frags: row/col = lane&31, k = (lane>>5)*8+j)
  const int l31 = lane & 31;
  const int aOff = ((lane >> 4) & 1) * 2048 + (lane & 15) * 64;
  const int sl0 = ((lane >> 5) * 16) ^ ((lane & 8) << 2);   // kstep even slot
  const int sl1 = sl0 ^ 32;                                  // kstep odd slot
  const int wd4 = wd * 4096;

  f32x16 acc[NSEG][2];
#pragma unroll
  for (int s = 0; s < NSEG; ++s)
#pragma unroll
    for (int m = 0; m < 2; ++m)
#pragma unroll
      for (int e = 0; e < 16; ++e) acc[s][m][e] = 0.f;

#define STAGE_A(t_, h_) do { int buf_ = (t_) & 1;                                   \
    const unsigned short* s0_ = Xb + (size_t)(m0 + (h_) * 128 + row_st) * K_DIM + (t_) * 64 + ke_st; \
    __builtin_amdgcn_global_load_lds((gas_ptr)s0_, (lds_ptr)(smem + buf_ * 32768 + (h_) * 16384 + ldsd), 16, 0, 0); \
    const unsigned short* s1_ = Xb + (size_t)(m0 + (h_) * 128 + row_st + 64) * K_DIM + (t_) * 64 + ke_st; \
    __builtin_amdgcn_global_load_lds((gas_ptr)s1_, (lds_ptr)(smem + buf_ * 32768 + (h_) * 16384 + ldsd + 8192), 16, 0, 0); \
  } while (0)

#define STAGE_B(t_, h_, bb_) do {                                                   \
    int e0_ = (h_) * 128 + row_st;                                                  \
    const unsigned short* s0_ = Wb + (size_t)(e0_ >> 6) * (N_DIM * K_DIM) + (size_t)(n0 + (e0_ & 63)) * K_DIM + (t_) * 64 + ke_st; \
    __builtin_amdgcn_global_load_lds((gas_ptr)s0_, (lds_ptr)(smem + 65536 + (bb_) * 32768 + (h_) * 16384 + ldsd), 16, 0, 0); \
    int e1_ = e0_ + 64;                                                             \
    const unsigned short* s1_ = Wb + (size_t)(e1_ >> 6) * (N_DIM * K_DIM) + (size_t)(n0 + (e1_ & 63)) * K_DIM + (t_) * 64 + ke_st; \
    __builtin_amdgcn_global_load_lds((gas_ptr)s1_, (lds_ptr)(smem + 65536 + (bb_) * 32768 + (h_) * 16384 + ldsd + 8192), 16, 0, 0); \
  } while (0)

#define MFMA32(a_, b_, c_) __builtin_amdgcn_mfma_f32_32x32x16_bf16(a_, b_, c_, 0, 0, 0)

#define PHASE(p_, STAGE_STMT, TAIL_STMT) do {                                       \
    const int koff_ = ((p_) >> 1) * 1024 + (((p_) & 1) ? sl1 : sl0) + aOff;         \
    bf16x8 a0_ = *(const bf16x8*)(Ab + koff_);                                      \
    bf16x8 a1_ = *(const bf16x8*)(Ab + 4096 + koff_);                               \
    bf16x8 b0_ = *(const bf16x8*)(Bb + wd4 + koff_);                                \
    bf16x8 b1_ = *(const bf16x8*)(Bb + 8192 + wd4 + koff_);                         \
    bf16x8 b2_ = *(const bf16x8*)(Bb + 16384 + wd4 + koff_);                        \
    bf16x8 b3_ = *(const bf16x8*)(Bb + 24576 + wd4 + koff_);                        \
    STAGE_STMT;                                                                     \
    asm volatile("s_barrier" ::: "memory");                                         \
    asm volatile("s_waitcnt lgkmcnt(0)" ::: "memory");                              \
    __builtin_amdgcn_s_setprio(1);                                                  \
    acc[0][0] = MFMA32(a0_, b0_, acc[0][0]);                                        \
    acc[1][0] = MFMA32(a0_, b1_, acc[1][0]);                                        \
    acc[2][0] = MFMA32(a0_, b2_, acc[2][0]);                                        \
    acc[3][0] = MFMA32(a0_, b3_, acc[3][0]);                                        \
    acc[0][1] = MFMA32(a1_, b0_, acc[0][1]);                                        \
    acc[1][1] = MFMA32(a1_, b1_, acc[1][1]);                                        \
    acc[2][1] = MFMA32(a1_, b2_, acc[2][1]);                                        \
    acc[3][1] = MFMA32(a1_, b3_, acc[3][1]);                                        \
    __builtin_amdgcn_s_setprio(0);                                                  \
    TAIL_STMT;                                                                      \
    asm volatile("s_barrier" ::: "memory");                                         \
  } while (0)

  // ---- prologue: A(0) -> Abuf0, B(0) -> Bbuf0, B(1) -> Bbuf1 ----
  STAGE_A(0, 0); STAGE_A(0, 1);
  STAGE_B(0, 0, 0); STAGE_B(0, 1, 0);
  STAGE_B(1, 0, 1); STAGE_B(1, 1, 1);
  asm volatile("s_waitcnt vmcnt(4)" ::: "memory");
  asm volatile("s_barrier" ::: "memory");

  int bc = 0, bs = 2;   // current / stage-target B buffer (mod 3)
  for (int t = 0; t < NT; ++t) {
    const char* Ab = smem + (t & 1) * 32768 + wm * 8192;
    const char* Bb = smem + 65536 + bc * 32768;

    PHASE(0, { if (t + 1 < NT) STAGE_A(t + 1, 0); }, {});
    PHASE(1, { if (t + 1 < NT) STAGE_A(t + 1, 1); }, {});
    PHASE(2, { if (t + 2 < NT) STAGE_B(t + 2, 0, bs); }, {});
    PHASE(3, { if (t + 2 < NT) STAGE_B(t + 2, 1, bs); },
          {
            if (t < NT - 2) { asm volatile("s_waitcnt vmcnt(4)" ::: "memory"); }
            else if (t == NT - 2) { asm volatile("s_waitcnt vmcnt(0)" ::: "memory"); }
          });
    bc = (bc == 2) ? 0 : bc + 1;
    bs = (bs == 2) ? 0 : bs + 1;
  }

  // ---------------- epilogue ----------------
  // 32x32 C/D layout: col = lane&31 (d), row = (reg&3)+8*(reg>>2)+4*(lane>>5)
  const int d = n0 + wd * 32 + l31;
  float bsv[NSEG], thv[NSEG];
#pragma unroll
  for (int s = 0; s < NSEG; ++s) {
    bsv[s] = b_seg[s * N_DIM + d];
    thv[s] = thr[s * N_DIM + d];
  }
  const int rbase = m0 + wm * 64 + ((lane >> 5) << 2);
#pragma unroll
  for (int mf = 0; mf < 2; ++mf) {
#pragma unroll
    for (int g = 0; g < 4; ++g) {
#pragma unroll
      for (int r = 0; r < 4; ++r) {
        const int brow = rbase + mf * 32 + g * 8 + r;
        const float4 gt = *(const float4*)(gates + (size_t)brow * 4);
        const float gv[NSEG] = {gt.x, gt.y, gt.z, gt.w};
        float sum = 0.f, prod = 1.f;
#pragma unroll
        for (int s = 0; s < NSEG; ++s) {
          const float seg = acc[s][mf][g * 4 + r] + bsv[s];
          const float pl = 1.f / (1.f + __expf(-5.f * (seg - thv[s])));
          const float st = seg * pl * gv[s];
          sum += st;
          prod *= st;
        }
        const float gm = sqrtf(sqrtf(fabsf(prod)));   // |prod|^(1/4)
        out[(size_t)brow * N_DIM + d] = sum + 0.1f * (prod < 0.f ? -gm : gm);
      }
    }
  }
#undef STAGE_A
#undef STAGE_B
#undef PHASE
#undef MFMA32
}

extern "C" void kernel_launch(void* const* d_in, const int* in_sizes, int n_in,
                              void* d_out, int out_size, void* d_ws, size_t ws_size,
                              hipStream_t stream) {
  const float* x      = (const float*)d_in[0];
  const float* W_seg  = (const float*)d_in[1];
  const float* b_seg  = (const float*)d_in[2];
  const float* thr    = (const float*)d_in[3];
  const float* W_gate = (const float*)d_in[4];
  const float* b_gate = (const float*)d_in[5];
  float* out = (float*)d_out;

  // workspace layout: x_bf16 (32MB) | W_bf16 (32MB) | gates (128KB)
  unsigned short* xb = (unsigned short*)d_ws;
  unsigned short* wb = xb + (size_t)B_DIM * K_DIM;
  float* gates = (float*)(wb + (size_t)NSEG * N_DIM * K_DIM);

  xconv_gates_kernel<<<B_DIM, 256, 0, stream>>>(x, W_gate, b_gate, xb, gates);
  convert_kernel<<<2048, 256, 0, stream>>>(W_seg, wb, NSEG * N_DIM * K_DIM / 8);

  hipFuncSetAttribute((const void*)seg_gemm_kernel,
                      hipFuncAttributeMaxDynamicSharedMemorySize, 163840);
  seg_gemm_kernel<<<1024, 512, 163840, stream>>>(xb, wb, b_seg, thr, gates, out);
}